// Round 4
// baseline (126.470 us; speedup 1.0000x reference)
//
#include <hip/hip_runtime.h>
#include <math.h>
#include <stdint.h>

#define NEGV -1e9f
typedef float f32x4 __attribute__((ext_vector_type(4)));
typedef short bf16x8 __attribute__((ext_vector_type(8)));
typedef unsigned int u32x4 __attribute__((ext_vector_type(4)));

constexpr int B_ = 16, N_ = 1024, M_ = 128, D_ = 768;
constexpr int NCH = 12;  // 768/64 chunks

// ws layout (bytes):
constexpr size_t OFF_QLOGP = 0;         // f32[16*128*12]  = 98304 B
constexpr size_t OFF_CLOG  = 98304;     // f32[16*1024]    = 65536 B
constexpr size_t OFF_ROWMAX= 163840;    // f32[16*1024]
constexpr size_t OFF_WQ2C  = 229376;    // f32[16*1024]
constexpr size_t OFF_BCTX  = 294912;    // f32[16*768]     = 49152 B
constexpr size_t OFF_QIMG  = 344064;    // QwH, QwL, QtH, QtL
constexpr size_t SZ_QIMG   = 3145728;   // 16 b * 12 ch * 16384 B
constexpr size_t OFF_CIMG  = OFF_QIMG + 4 * SZ_QIMG;   // CiH, CiL
constexpr size_t SZ_CIMG   = 25165824;  // 512 tiles * 12 ch * 4096 B
constexpr size_t WS_NEED   = OFF_CIMG + 2 * SZ_CIMG;   // ~63.3 MB

__device__ __forceinline__ unsigned short bf_rne(float x) {
    unsigned u = __float_as_uint(x);
    return (unsigned short)((u + 0x7fffu + ((u >> 16) & 1u)) >> 16);
}
__device__ __forceinline__ void splitf(float x, unsigned short& h, unsigned short& l) {
    unsigned short hb = bf_rne(x);
    float hf = __uint_as_float((unsigned)hb << 16);
    h = hb;
    l = bf_rne(x - hf);
}
__device__ __forceinline__ void gl_lds16(const void* g, void* l) {
    __builtin_amdgcn_global_load_lds(
        (const __attribute__((address_space(1))) void*)g,
        (__attribute__((address_space(3))) void*)l, 16, 0, 0);
}

__global__ __launch_bounds__(256) void k_qlogit(const float* __restrict__ Q,
                                                const float* __restrict__ w2,
                                                float* __restrict__ qlog) {
    int idx  = blockIdx.x * 4 + (threadIdx.x >> 6);
    int lane = threadIdx.x & 63;
    const float* q = Q + (size_t)idx * D_;
    float s = 0.f;
    for (int k = lane; k < D_; k += 64) s += q[k] * w2[k];
#pragma unroll
    for (int off = 32; off; off >>= 1) s += __shfl_xor(s, off);
    if (lane == 0) qlog[idx] = s;
}

// One-shot Q conversion + q_logit partials.
// QwH/QwL: (w3-folded) per (b,chunk): [j=128][g=8 swz g^(j&7)][8 bf16]  (16 KB/chunk)
// QtH/QtL: (raw, transposed) per (b,chunk): [dd=64][gj=16 swz gj^(dd&7)][8 bf16]
__global__ __launch_bounds__(256) void k_prep(const float* __restrict__ Q,
                                              const float* __restrict__ w2,
                                              const float* __restrict__ w3,
                                              char* __restrict__ qwh, char* __restrict__ qwl,
                                              char* __restrict__ qth, char* __restrict__ qtl,
                                              float* __restrict__ qlogp) {
    int b = blockIdx.x / NCH, c = blockIdx.x % NCH;
    int t = threadIdx.x;
    __shared__ unsigned sT[128][66];
    __shared__ float sW2[64], sW3[64];
    if (t < 64) sW2[t] = w2[c * 64 + t];
    else if (t < 128) sW3[t - 64] = w3[c * 64 + (t - 64)];
    __syncthreads();
    int j = t >> 1, half = t & 1;
    const float* src = Q + ((size_t)(b * M_ + j)) * D_ + c * 64 + half * 32;
    unsigned short hs[32], ls[32];
    float qsum = 0.f;
#pragma unroll
    for (int u = 0; u < 8; ++u) {
        float4 v = *(const float4*)(src + u * 4);
        float f[4] = {v.x, v.y, v.z, v.w};
#pragma unroll
        for (int e = 0; e < 4; ++e) {
            int idx = u * 4 + e, d = half * 32 + idx;
            qsum += f[e] * sW2[d];
            unsigned short rh, rl; splitf(f[e], rh, rl);
            sT[j][d] = ((unsigned)rh << 16) | (unsigned)rl;
            unsigned short h, l; splitf(f[e] * sW3[d], h, l);
            hs[idx] = h; ls[idx] = l;
        }
    }
    qsum += __shfl_xor(qsum, 1);
    if (half == 0) qlogp[(size_t)(b * M_ + j) * NCH + c] = qsum;
    size_t cb = ((size_t)(b * NCH + c)) * 16384;
#pragma unroll
    for (int u2 = 0; u2 < 4; ++u2) {
        int g = half * 4 + u2;
        bf16x8 hv, lv;
#pragma unroll
        for (int e = 0; e < 8; ++e) { hv[e] = (short)hs[u2 * 8 + e]; lv[e] = (short)ls[u2 * 8 + e]; }
        size_t off = cb + (size_t)j * 128 + (size_t)((g ^ (j & 7)) * 16);
        *(bf16x8*)(qwh + off) = hv;
        *(bf16x8*)(qwl + off) = lv;
    }
    __syncthreads();
#pragma unroll
    for (int u = 0; u < 4; ++u) {
        int id = t * 4 + u;
        int dd = id >> 4, gj = id & 15;
        bf16x8 hv, lv;
#pragma unroll
        for (int e = 0; e < 8; ++e) {
            unsigned p = sT[gj * 8 + e][dd];
            hv[e] = (short)(p >> 16); lv[e] = (short)(p & 0xffffu);
        }
        size_t off = cb + (size_t)dd * 256 + (size_t)((gj ^ (dd & 7)) * 16);
        *(bf16x8*)(qth + off) = hv;
        *(bf16x8*)(qtl + off) = lv;
    }
}

// One-shot C conversion: raw-C split-bf16 pre-swizzled phase-1 A images + exact c_logit.
// Image per (tile=b*32+rt, chunk): [32 r][8 g swz g^(r&7)][8 bf16] (4 KB)
__global__ __launch_bounds__(256) void k_cprep(const float* __restrict__ C,
                                               const float* __restrict__ w1,
                                               char* __restrict__ cih, char* __restrict__ cil,
                                               float* __restrict__ clog) {
    const int bid = (blockIdx.x & 7) * 64 + (blockIdx.x >> 3);  // same XCD swizzle as k_main
    const int b = bid >> 5, rt = bid & 31;
    const int t = threadIdx.x;
    __shared__ float sW1[D_];
    for (int k = t; k < D_; k += 256) sW1[k] = w1[k];
    __syncthreads();
    const int cr = t >> 3, ckq = t & 7;
    const float* Cb = C + ((size_t)(b * N_ + rt * 32)) * D_;
    float clogacc = 0.f;
    size_t ibase = (size_t)(bid * NCH) * 4096;
#pragma unroll 4
    for (int kidx = 0; kidx < NCH; ++kidx) {
        const float* p = Cb + (size_t)cr * D_ + kidx * 64 + ckq * 8;
        float4 a  = *(const float4*)p;
        float4 bb = *(const float4*)(p + 4);
        float cc[8] = {a.x, a.y, a.z, a.w, bb.x, bb.y, bb.z, bb.w};
        bf16x8 hv, lv;
        int kk = kidx * 64 + ckq * 8;
#pragma unroll
        for (int e = 0; e < 8; ++e) {
            clogacc += cc[e] * sW1[kk + e];
            unsigned short h, l; splitf(cc[e], h, l);
            hv[e] = (short)h; lv[e] = (short)l;
        }
        size_t off = ibase + (size_t)kidx * 4096 + cr * 128 + ((ckq ^ (cr & 7)) * 16);
        *(bf16x8*)(cih + off) = hv;
        *(bf16x8*)(cil + off) = lv;
    }
    clogacc += __shfl_xor(clogacc, 1);
    clogacc += __shfl_xor(clogacc, 2);
    clogacc += __shfl_xor(clogacc, 4);
    if (ckq == 0) clog[b * N_ + rt * 32 + cr] = clogacc;
}

// 512 blocks (XCD-swizzled): b = bid>>5, 32 rows. 4 waves: rg = w>>1, jh = w&1.
// Phase 1 is pure global_load_lds staging + MFMA (no conversion VALU).
__global__ __launch_bounds__(256, 2) void k_main_fast(const float* __restrict__ C,
                                                      const int* __restrict__ c_mask,
                                                      const int* __restrict__ q_mask,
                                                      const float* __restrict__ clog,
                                                      const float* __restrict__ qlogp,
                                                      const char* __restrict__ qwh,
                                                      const char* __restrict__ qwl,
                                                      const char* __restrict__ qth,
                                                      const char* __restrict__ qtl,
                                                      const char* __restrict__ cih,
                                                      const char* __restrict__ cil,
                                                      float* __restrict__ rowmax,
                                                      float* __restrict__ out) {
    const int bid = (blockIdx.x & 7) * 64 + (blockIdx.x >> 3);
    const int b  = bid >> 5;
    const int r0 = (bid & 31) * 32;
    const int t  = threadIdx.x;
    const int wv = t >> 6, lane = t & 63;
    const int rg = wv >> 1, jh = wv & 1;
    const int q4 = (t & 63) >> 4, c15 = t & 15;

    const float* Cb = C + ((size_t)(b * N_ + r0)) * D_;

    __shared__ __align__(16) char uni[49152];
    __shared__ float sQlog[M_];
    __shared__ int   sQmask[M_];
    __shared__ float sClog[32];
    __shared__ float sRedR[64], sRedM[64], sRedS[64];

    char* sCiH = uni;             // phase1 A: [32 r][8 g][16B] swz g^(r&7)  (4 KB)
    char* sCiL = uni + 4096;
    char* sQH  = uni + 8192;      // phase1 B: chunk image (16 KB)
    char* sQL  = uni + 24576;
    char* sPH  = uni;             // phase2/3: [32 r][16 gj][16B] swz gj^(r&7) (8 KB)
    char* sPL  = uni + 8192;
    char* sQtH = uni + 16384;     // phase3 B: chunk image (16 KB)
    char* sQtL = uni + 32768;

    if (t < M_) {
        const float* qp = qlogp + (size_t)(b * M_ + t) * NCH;
        float4 x = *(const float4*)qp, y = *(const float4*)(qp + 4), z = *(const float4*)(qp + 8);
        sQlog[t] = ((x.x + x.y) + (x.z + x.w)) + ((y.x + y.y) + (y.z + y.w)) +
                   ((z.x + z.y) + (z.z + z.w));
        sQmask[t] = q_mask[b * M_ + t];
    }
    if (t < 32) sClog[t] = clog[b * N_ + r0 + t];

    f32x4 acc[4] = {};
    const size_t qcb = (size_t)(b * NCH) * 16384;
    const size_t ccb = (size_t)(bid * NCH) * 4096;

    // ---- Phase 1: S = C @ (w3*Q)^T ----
    for (int kidx = 0; kidx < NCH; ++kidx) {
        __syncthreads();
        {
            size_t cgb = ccb + (size_t)kidx * 4096;
            int off = wv * 1024;
            gl_lds16(cih + cgb + off + lane * 16, sCiH + off);
            gl_lds16(cil + cgb + off + lane * 16, sCiL + off);
            size_t gb = qcb + (size_t)kidx * 16384;
#pragma unroll
            for (int it = 0; it < 4; ++it) {
                int qo = it * 4096 + wv * 1024;
                gl_lds16(qwh + gb + qo + lane * 16, sQH + qo);
                gl_lds16(qwl + gb + qo + lane * 16, sQL + qo);
            }
        }
        __syncthreads();
        const int arow = rg * 16 + c15;
#pragma unroll
        for (int ks = 0; ks < 2; ++ks) {
            int g  = ks * 4 + q4;
            int pg = (g ^ (c15 & 7)) * 16;
            bf16x8 ah = *(const bf16x8*)(sCiH + arow * 128 + pg);
            bf16x8 al = *(const bf16x8*)(sCiL + arow * 128 + pg);
#pragma unroll
            for (int jt = 0; jt < 4; ++jt) {
                int jr = jh * 64 + jt * 16 + c15;
                bf16x8 bh = *(const bf16x8*)(sQH + jr * 128 + pg);
                bf16x8 bl = *(const bf16x8*)(sQL + jr * 128 + pg);
                acc[jt] = __builtin_amdgcn_mfma_f32_16x16x32_bf16(ah, bh, acc[jt], 0, 0, 0);
                acc[jt] = __builtin_amdgcn_mfma_f32_16x16x32_bf16(ah, bl, acc[jt], 0, 0, 0);
                acc[jt] = __builtin_amdgcn_mfma_f32_16x16x32_bf16(al, bh, acc[jt], 0, 0, 0);
            }
        }
    }

    // ---- Phase 2: logits + masked softmax ----
    float qlg[4]; int qmv[4];
#pragma unroll
    for (int jt = 0; jt < 4; ++jt) {
        int j = jh * 64 + jt * 16 + c15;
        qlg[jt] = sQlog[j]; qmv[jt] = sQmask[j];
    }
    int cmv[4]; float clgr[4];
#pragma unroll
    for (int rr = 0; rr < 4; ++rr) {
        int row = rg * 16 + q4 * 4 + rr;
        cmv[rr]  = c_mask[b * N_ + r0 + row];
        clgr[rr] = sClog[row];
    }
    float mv[4][4], rmx[4], mmx[4];
#pragma unroll
    for (int rr = 0; rr < 4; ++rr) { rmx[rr] = -INFINITY; mmx[rr] = -INFINITY; }
#pragma unroll
    for (int jt = 0; jt < 4; ++jt)
#pragma unroll
        for (int rr = 0; rr < 4; ++rr) {
            float val = acc[jt][rr] + clgr[rr] + qlg[jt];
            float m   = (cmv[rr] | qmv[jt]) ? NEGV : val;
            mv[jt][rr] = m;
            rmx[rr] = fmaxf(rmx[rr], val);
            mmx[rr] = fmaxf(mmx[rr], m);
        }
#pragma unroll
    for (int rr = 0; rr < 4; ++rr)
#pragma unroll
        for (int off = 8; off; off >>= 1) {
            rmx[rr] = fmaxf(rmx[rr], __shfl_xor(rmx[rr], off));
            mmx[rr] = fmaxf(mmx[rr], __shfl_xor(mmx[rr], off));
        }
    if (c15 == 0) {
#pragma unroll
        for (int rr = 0; rr < 4; ++rr) {
            int row = rg * 16 + q4 * 4 + rr;
            sRedR[row * 2 + jh] = rmx[rr];
            sRedM[row * 2 + jh] = mmx[rr];
        }
    }
    __syncthreads();
    float Mm[4], sum[4];
#pragma unroll
    for (int rr = 0; rr < 4; ++rr) {
        int row = rg * 16 + q4 * 4 + rr;
        float Mraw = fmaxf(sRedR[row * 2], sRedR[row * 2 + 1]);
        Mm[rr] = fmaxf(sRedM[row * 2], sRedM[row * 2 + 1]);
        if (jh == 0 && c15 == 0) rowmax[b * N_ + r0 + row] = Mraw;
        sum[rr] = 0.f;
    }
    float p[4][4];
#pragma unroll
    for (int jt = 0; jt < 4; ++jt)
#pragma unroll
        for (int rr = 0; rr < 4; ++rr) {
            float e = __expf(mv[jt][rr] - Mm[rr]);
            p[jt][rr] = e; sum[rr] += e;
        }
#pragma unroll
    for (int rr = 0; rr < 4; ++rr) {
#pragma unroll
        for (int off = 8; off; off >>= 1) sum[rr] += __shfl_xor(sum[rr], off);
        if (c15 == 0) sRedS[(rg * 16 + q4 * 4 + rr) * 2 + jh] = sum[rr];
    }
    __syncthreads();
#pragma unroll
    for (int rr = 0; rr < 4; ++rr) {
        int row = rg * 16 + q4 * 4 + rr;
        float inv = 1.f / (sRedS[row * 2] + sRedS[row * 2 + 1]);
#pragma unroll
        for (int jt = 0; jt < 4; ++jt) {
            float P = p[jt][rr] * inv;
            unsigned short h, l; splitf(P, h, l);
            int j = jh * 64 + jt * 16 + c15;
            int addr = row * 256 + (((j >> 3) ^ (row & 7)) * 16) + (j & 7) * 2;
            *(short*)(sPH + addr) = (short)h;
            *(short*)(sPL + addr) = (short)l;
        }
    }

    // ---- Phase 3: A = P @ Q + fused epilogue ----
    for (int dc = 0; dc < NCH; ++dc) {
        __syncthreads();
        {
            size_t gb = qcb + (size_t)dc * 16384;
#pragma unroll
            for (int it = 0; it < 4; ++it) {
                int off = it * 4096 + wv * 1024;
                gl_lds16(qth + gb + off + lane * 16, sQtH + off);
                gl_lds16(qtl + gb + off + lane * 16, sQtL + off);
            }
        }
        __syncthreads();
        f32x4 acc2[2] = {};
        const int prow = rg * 16 + c15;
#pragma unroll
        for (int ks2 = 0; ks2 < 4; ++ks2) {
            int gja = ks2 * 4 + q4;
            int pgp = (gja ^ (prow & 7)) * 16;
            bf16x8 ah = *(const bf16x8*)(sPH + prow * 256 + pgp);
            bf16x8 al = *(const bf16x8*)(sPL + prow * 256 + pgp);
#pragma unroll
            for (int dt = 0; dt < 2; ++dt) {
                int dr  = jh * 32 + dt * 16 + c15;
                int pgq = (gja ^ (dr & 7)) * 16;
                bf16x8 bh = *(const bf16x8*)(sQtH + dr * 256 + pgq);
                bf16x8 bl = *(const bf16x8*)(sQtL + dr * 256 + pgq);
                acc2[dt] = __builtin_amdgcn_mfma_f32_16x16x32_bf16(ah, bh, acc2[dt], 0, 0, 0);
                acc2[dt] = __builtin_amdgcn_mfma_f32_16x16x32_bf16(ah, bl, acc2[dt], 0, 0, 0);
                acc2[dt] = __builtin_amdgcn_mfma_f32_16x16x32_bf16(al, bh, acc2[dt], 0, 0, 0);
            }
        }
#pragma unroll
        for (int dt = 0; dt < 2; ++dt)
#pragma unroll
            for (int rr = 0; rr < 4; ++rr) {
                int row  = rg * 16 + q4 * 4 + rr;
                int dcol = dc * 64 + jh * 32 + dt * 16 + c15;
                float a = acc2[dt][rr];
                float c = Cb[(size_t)row * D_ + dcol];
                size_t ob = (size_t)(b * N_ + r0 + row) * 3072;
                out[ob + dcol] = c;
                out[ob + 768 + dcol] = a;
                out[ob + 1536 + dcol] = c * a;
            }
    }
}

// ---------------- fallback (R2-proven) ----------------
__global__ __launch_bounds__(256, 2) void k_main_fb(const float* __restrict__ C,
                                                    const float* __restrict__ Q,
                                                    const int* __restrict__ c_mask,
                                                    const int* __restrict__ q_mask,
                                                    const float* __restrict__ w1,
                                                    const float* __restrict__ w3,
                                                    const float* __restrict__ qlog,
                                                    float* __restrict__ rowmax,
                                                    float* __restrict__ out) {
    const int bid = (blockIdx.x & 7) * 64 + (blockIdx.x >> 3);
    const int b  = bid >> 5;
    const int r0 = (bid & 31) * 32;
    const int t  = threadIdx.x;
    const int wv = t >> 6;
    const int rg = wv >> 1, jh = wv & 1;
    const int q4 = (t & 63) >> 4, c15 = t & 15;

    const float* Cb = C + ((size_t)(b * N_ + r0)) * D_;
    const float* Qb = Q + (size_t)b * M_ * D_;

    __shared__ __align__(16) char uni[49152];
    __shared__ float sW1[D_], sW3[D_];
    __shared__ float sQlog[M_];
    __shared__ int   sQmask[M_];
    __shared__ float sClog[32];
    __shared__ float sRedR[64], sRedM[64], sRedS[64];

    char* sCwH = uni;
    char* sCwL = uni + 4096;
    char* sQH  = uni + 8192;
    char* sQL  = uni + 24576;
    char* sPt  = uni;
    char* sQtP = uni + 16384;

    for (int k = t; k < D_; k += 256) { sW1[k] = w1[k]; sW3[k] = w3[k]; }
    if (t < M_) { sQlog[t] = qlog[b * M_ + t]; sQmask[t] = q_mask[b * M_ + t]; }

    f32x4 acc[4] = {};
    float clog = 0.f;
    const int cr = t >> 3, ckq = t & 7;
    const int qj = t >> 1, qk0 = (t & 1) * 32;

    for (int kb = 0; kb < D_; kb += 64) {
        __syncthreads();
        {
            const float* p = Cb + (size_t)cr * D_ + kb + ckq * 8;
            float4 a  = *(const float4*)p;
            float4 bb = *(const float4*)(p + 4);
            float cc[8] = {a.x, a.y, a.z, a.w, bb.x, bb.y, bb.z, bb.w};
            bf16x8 hv, lv;
            int kk = kb + ckq * 8;
#pragma unroll
            for (int e = 0; e < 8; ++e) {
                clog += cc[e] * sW1[kk + e];
                unsigned short h, l;
                splitf(cc[e] * sW3[kk + e], h, l);
                hv[e] = (short)h; lv[e] = (short)l;
            }
            int pg = (ckq ^ (cr & 7)) * 16;
            *(bf16x8*)(sCwH + cr * 128 + pg) = hv;
            *(bf16x8*)(sCwL + cr * 128 + pg) = lv;
        }
        {
            const float* p = Qb + (size_t)qj * D_ + kb + qk0;
#pragma unroll
            for (int u = 0; u < 4; ++u) {
                float4 a  = *(const float4*)(p + u * 8);
                float4 bb = *(const float4*)(p + u * 8 + 4);
                float qq[8] = {a.x, a.y, a.z, a.w, bb.x, bb.y, bb.z, bb.w};
                bf16x8 hv, lv;
#pragma unroll
                for (int e = 0; e < 8; ++e) {
                    unsigned short h, l;
                    splitf(qq[e], h, l);
                    hv[e] = (short)h; lv[e] = (short)l;
                }
                int g  = (t & 1) * 4 + u;
                int pg = (g ^ (qj & 7)) * 16;
                *(bf16x8*)(sQH + qj * 128 + pg) = hv;
                *(bf16x8*)(sQL + qj * 128 + pg) = lv;
            }
        }
        __syncthreads();
        const int arow = rg * 16 + c15;
#pragma unroll
        for (int ks = 0; ks < 2; ++ks) {
            int g  = ks * 4 + q4;
            int pg = (g ^ (c15 & 7)) * 16;
            bf16x8 ah = *(const bf16x8*)(sCwH + arow * 128 + pg);
            bf16x8 al = *(const bf16x8*)(sCwL + arow * 128 + pg);
#pragma unroll
            for (int jt = 0; jt < 4; ++jt) {
                int jr = jh * 64 + jt * 16 + c15;
                bf16x8 bh = *(const bf16x8*)(sQH + jr * 128 + pg);
                bf16x8 bl = *(const bf16x8*)(sQL + jr * 128 + pg);
                acc[jt] = __builtin_amdgcn_mfma_f32_16x16x32_bf16(ah, bh, acc[jt], 0, 0, 0);
                acc[jt] = __builtin_amdgcn_mfma_f32_16x16x32_bf16(ah, bl, acc[jt], 0, 0, 0);
                acc[jt] = __builtin_amdgcn_mfma_f32_16x16x32_bf16(al, bh, acc[jt], 0, 0, 0);
            }
        }
    }

    clog += __shfl_xor(clog, 1); clog += __shfl_xor(clog, 2); clog += __shfl_xor(clog, 4);
    if ((t & 7) == 0) sClog[cr] = clog;
    __syncthreads();

    float qlg[4]; int qmv[4];
#pragma unroll
    for (int jt = 0; jt < 4; ++jt) {
        int j = jh * 64 + jt * 16 + c15;
        qlg[jt] = sQlog[j]; qmv[jt] = sQmask[j];
    }
    int cmv[4]; float clgr[4];
#pragma unroll
    for (int rr = 0; rr < 4; ++rr) {
        int row = rg * 16 + q4 * 4 + rr;
        cmv[rr]  = c_mask[b * N_ + r0 + row];
        clgr[rr] = sClog[row];
    }
    float mv[4][4], rmx[4], mmx[4];
#pragma unroll
    for (int rr = 0; rr < 4; ++rr) { rmx[rr] = -INFINITY; mmx[rr] = -INFINITY; }
#pragma unroll
    for (int jt = 0; jt < 4; ++jt)
#pragma unroll
        for (int rr = 0; rr < 4; ++rr) {
            float val = acc[jt][rr] + clgr[rr] + qlg[jt];
            float m   = (cmv[rr] | qmv[jt]) ? NEGV : val;
            mv[jt][rr] = m;
            rmx[rr] = fmaxf(rmx[rr], val);
            mmx[rr] = fmaxf(mmx[rr], m);
        }
#pragma unroll
    for (int rr = 0; rr < 4; ++rr)
#pragma unroll
        for (int off = 8; off; off >>= 1) {
            rmx[rr] = fmaxf(rmx[rr], __shfl_xor(rmx[rr], off));
            mmx[rr] = fmaxf(mmx[rr], __shfl_xor(mmx[rr], off));
        }
    if (c15 == 0) {
#pragma unroll
        for (int rr = 0; rr < 4; ++rr) {
            int row = rg * 16 + q4 * 4 + rr;
            sRedR[row * 2 + jh] = rmx[rr];
            sRedM[row * 2 + jh] = mmx[rr];
        }
    }
    __syncthreads();
    float Mm[4], sum[4];
#pragma unroll
    for (int rr = 0; rr < 4; ++rr) {
        int row = rg * 16 + q4 * 4 + rr;
        float Mraw = fmaxf(sRedR[row * 2], sRedR[row * 2 + 1]);
        Mm[rr] = fmaxf(sRedM[row * 2], sRedM[row * 2 + 1]);
        if (jh == 0 && c15 == 0) rowmax[b * N_ + r0 + row] = Mraw;
        sum[rr] = 0.f;
    }
    float p[4][4];
#pragma unroll
    for (int jt = 0; jt < 4; ++jt)
#pragma unroll
        for (int rr = 0; rr < 4; ++rr) {
            float e = __expf(mv[jt][rr] - Mm[rr]);
            p[jt][rr] = e; sum[rr] += e;
        }
#pragma unroll
    for (int rr = 0; rr < 4; ++rr) {
#pragma unroll
        for (int off = 8; off; off >>= 1) sum[rr] += __shfl_xor(sum[rr], off);
        if (c15 == 0) sRedS[(rg * 16 + q4 * 4 + rr) * 2 + jh] = sum[rr];
    }
    __syncthreads();
#pragma unroll
    for (int rr = 0; rr < 4; ++rr) {
        int row = rg * 16 + q4 * 4 + rr;
        float inv = 1.f / (sRedS[row * 2] + sRedS[row * 2 + 1]);
#pragma unroll
        for (int jt = 0; jt < 4; ++jt) {
            float P = p[jt][rr] * inv;
            unsigned short h, l; splitf(P, h, l);
            unsigned pk = ((unsigned)h << 16) | (unsigned)l;
            int j  = jh * 64 + jt * 16 + c15;
            int gu = j >> 2;
            *(unsigned*)(sPt + row * 512 + ((gu ^ (row & 7)) * 16) + (j & 3) * 4) = pk;
        }
    }

    const int pj = t >> 1, pdh = (t & 1) * 32;
    for (int d0 = 0; d0 < D_; d0 += 64) {
        __syncthreads();
        {
            const float* p = Qb + (size_t)pj * D_ + d0 + pdh;
            int gu = pj >> 2, joff = (pj & 3) * 4;
#pragma unroll
            for (int u = 0; u < 8; ++u) {
                float4 a = *(const float4*)(p + u * 4);
                float qq[4] = {a.x, a.y, a.z, a.w};
#pragma unroll
                for (int e = 0; e < 4; ++e) {
                    unsigned short h, l; splitf(qq[e], h, l);
                    int d = pdh + u * 4 + e;
                    *(unsigned*)(sQtP + d * 512 + ((gu ^ (d & 7)) * 16) + joff) =
                        ((unsigned)h << 16) | (unsigned)l;
                }
            }
        }
        __syncthreads();
        f32x4 acc2[2] = {};
        const int prow = rg * 16 + c15;
#pragma unroll
        for (int ks2 = 0; ks2 < 4; ++ks2) {
            int gu0 = ks2 * 8 + q4 * 2;
            u32x4 pa = *(const u32x4*)(sPt + prow * 512 + ((gu0 ^ (c15 & 7)) * 16));
            u32x4 pb = *(const u32x4*)(sPt + prow * 512 + (((gu0 + 1) ^ (c15 & 7)) * 16));
            bf16x8 phi, plo;
#pragma unroll
            for (int e = 0; e < 4; ++e) {
                phi[e]     = (short)(pa[e] >> 16); plo[e]     = (short)(pa[e] & 0xffffu);
                phi[e + 4] = (short)(pb[e] >> 16); plo[e + 4] = (short)(pb[e] & 0xffffu);
            }
#pragma unroll
            for (int dt = 0; dt < 2; ++dt) {
                int dr = jh * 32 + dt * 16 + c15;
                u32x4 qa = *(const u32x4*)(sQtP + dr * 512 + ((gu0 ^ (dr & 7)) * 16));
                u32x4 qb = *(const u32x4*)(sQtP + dr * 512 + (((gu0 + 1) ^ (dr & 7)) * 16));
                bf16x8 bh, bl;
#pragma unroll
                for (int e = 0; e < 4; ++e) {
                    bh[e]     = (short)(qa[e] >> 16); bl[e]     = (short)(qa[e] & 0xffffu);
                    bh[e + 4] = (short)(qb[e] >> 16); bl[e + 4] = (short)(qb[e] & 0xffffu);
                }
                acc2[dt] = __builtin_amdgcn_mfma_f32_16x16x32_bf16(phi, bh, acc2[dt], 0, 0, 0);
                acc2[dt] = __builtin_amdgcn_mfma_f32_16x16x32_bf16(phi, bl, acc2[dt], 0, 0, 0);
                acc2[dt] = __builtin_amdgcn_mfma_f32_16x16x32_bf16(plo, bh, acc2[dt], 0, 0, 0);
            }
        }
#pragma unroll
        for (int dt = 0; dt < 2; ++dt)
#pragma unroll
            for (int rr = 0; rr < 4; ++rr) {
                int row  = rg * 16 + q4 * 4 + rr;
                int dcol = d0 + jh * 32 + dt * 16 + c15;
                float a = acc2[dt][rr];
                float c = Cb[(size_t)row * D_ + dcol];
                size_t ob = (size_t)(b * N_ + r0 + row) * 3072;
                out[ob + dcol] = c;
                out[ob + 768 + dcol] = a;
                out[ob + 1536 + dcol] = c * a;
            }
    }
}

__global__ __launch_bounds__(256) void k_q2c(const float* __restrict__ rowmax,
                                             const int* __restrict__ c_mask,
                                             float* __restrict__ wq2c) {
    int b = blockIdx.x, t = threadIdx.x;
    __shared__ float red[8];
    float l[4];
#pragma unroll
    for (int u = 0; u < 4; ++u) {
        int i = t + u * 256;
        l[u] = (c_mask[b * N_ + i] != 0) ? NEGV : rowmax[b * N_ + i];
    }
    float mx = fmaxf(fmaxf(l[0], l[1]), fmaxf(l[2], l[3]));
#pragma unroll
    for (int off = 32; off; off >>= 1) mx = fmaxf(mx, __shfl_xor(mx, off));
    if ((t & 63) == 0) red[t >> 6] = mx;
    __syncthreads();
    mx = fmaxf(fmaxf(red[0], red[1]), fmaxf(red[2], red[3]));
    float e[4], s = 0.f;
#pragma unroll
    for (int u = 0; u < 4; ++u) { e[u] = __expf(l[u] - mx); s += e[u]; }
#pragma unroll
    for (int off = 32; off; off >>= 1) s += __shfl_xor(s, off);
    if ((t & 63) == 0) red[4 + (t >> 6)] = s;
    __syncthreads();
    s = red[4] + red[5] + red[6] + red[7];
    float inv = 1.f / s;
#pragma unroll
    for (int u = 0; u < 4; ++u) wq2c[b * N_ + t + u * 256] = e[u] * inv;
}

__global__ __launch_bounds__(256) void k_bctx(const float* __restrict__ C,
                                              const float* __restrict__ wq2c,
                                              float* __restrict__ Bctx) {
    int b  = blockIdx.x / 12;
    int c0 = (blockIdx.x % 12) * 64;
    int t  = threadIdx.x;
    int col = t & 63, ig = t >> 6;
    __shared__ float part[4][64];
    const float* wb = wq2c + b * N_;
    const float* Cb = C + (size_t)b * N_ * D_;
    float s = 0.f;
    for (int i = ig * 256; i < ig * 256 + 256; ++i)
        s += wb[i] * Cb[(size_t)i * D_ + c0 + col];
    part[ig][col] = s;
    __syncthreads();
    if (t < 64) Bctx[b * D_ + c0 + t] = part[0][t] + part[1][t] + part[2][t] + part[3][t];
}

__global__ __launch_bounds__(192) void k_final(const float* __restrict__ C,
                                               const float* __restrict__ Bctx,
                                               float* __restrict__ out) {
    int row = blockIdx.x;
    int b = row >> 10;
    int t = threadIdx.x;
    float4 c = *(const float4*)(C + (size_t)row * D_ + t * 4);
    float4 g = *(const float4*)(Bctx + (size_t)b * D_ + t * 4);
    *(float4*)(out + (size_t)row * 3072 + 2304 + t * 4) =
        make_float4(c.x * g.x, c.y * g.y, c.z * g.z, c.w * g.w);
}

extern "C" void kernel_launch(void* const* d_in, const int* in_sizes, int n_in,
                              void* d_out, int out_size, void* d_ws, size_t ws_size,
                              hipStream_t stream) {
    const float* C      = (const float*)d_in[0];
    const float* Q      = (const float*)d_in[1];
    const int*   c_mask = (const int*)d_in[2];
    const int*   q_mask = (const int*)d_in[3];
    const float* w1     = (const float*)d_in[4];
    const float* w2     = (const float*)d_in[5];
    const float* w3     = (const float*)d_in[6];
    float* out = (float*)d_out;
    char*  wsb = (char*)d_ws;

    float* qlogp  = (float*)(wsb + OFF_QLOGP);
    float* clog   = (float*)(wsb + OFF_CLOG);
    float* rowmax = (float*)(wsb + OFF_ROWMAX);
    float* wq2c   = (float*)(wsb + OFF_WQ2C);
    float* Bctx   = (float*)(wsb + OFF_BCTX);

    if (ws_size >= WS_NEED) {
        char* qwh = wsb + OFF_QIMG;
        char* qwl = qwh + SZ_QIMG;
        char* qth = qwl + SZ_QIMG;
        char* qtl = qth + SZ_QIMG;
        char* cih = wsb + OFF_CIMG;
        char* cil = cih + SZ_CIMG;
        k_prep<<<B_ * NCH, 256, 0, stream>>>(Q, w2, w3, qwh, qwl, qth, qtl, qlogp);
        k_cprep<<<512, 256, 0, stream>>>(C, w1, cih, cil, clog);
        k_main_fast<<<512, 256, 0, stream>>>(C, c_mask, q_mask, clog, qlogp,
                                             qwh, qwl, qth, qtl, cih, cil, rowmax, out);
    } else {
        float* qlog = (float*)(wsb + 0);
        k_qlogit<<<512, 256, 0, stream>>>(Q, w2, qlog);
        k_main_fb<<<512, 256, 0, stream>>>(C, Q, c_mask, q_mask, w1, w3, qlog, rowmax, out);
    }
    k_q2c<<<16, 256, 0, stream>>>(rowmax, c_mask, wq2c);
    k_bctx<<<192, 256, 0, stream>>>(C, wq2c, Bctx);
    k_final<<<16384, 192, 0, stream>>>(C, Bctx, out);
}